// Round 4
// baseline (145.250 us; speedup 1.0000x reference)
//
#include <hip/hip_runtime.h>
#include <math.h>

#define FREQ_DIM 256
#define TDIM 512
#define MODC 352
#define EPS 1e-5f

__device__ __forceinline__ float silu_f(float x) {
    return x / (1.0f + expf(-x));
}

// One MLP layer for R rows resident in LDS. Thread tid owns output column tid.
// Reads s_in (row stride in_stride), writes outp (row stride out_stride,
// LDS or global). 2-chunk-deep register prefetch of w to hide L2 latency.
template <int K, int NC, int R, bool POST_SILU>
__device__ __forceinline__ void mlp_stage(const float* s_in, int in_stride,
                                          const float* __restrict__ w,
                                          const float* __restrict__ bias,
                                          float* outp, int out_stride, int tid) {
    int j = tid;
    if (j >= NC) return;   // inactive cols: no barriers inside this function
    constexpr int UF = 8;

    float acc[R];
#pragma unroll
    for (int r = 0; r < R; ++r) acc[r] = 0.f;

    const float* wp = w + j;
    float wa[UF], wb[UF];
#pragma unroll
    for (int u = 0; u < UF; ++u) wa[u] = wp[(size_t)u * NC];
#pragma unroll
    for (int u = 0; u < UF; ++u) wb[u] = wp[(size_t)(UF + u) * NC];

    for (int k0 = 0; k0 < K; k0 += 2 * UF) {
        int kpa = k0 + 2 * UF; if (kpa > K - UF) kpa = K - UF;   // clamped (redundant) tail prefetch
        int kpb = k0 + 3 * UF; if (kpb > K - UF) kpb = K - UF;

        float wc[UF];
#pragma unroll
        for (int u = 0; u < UF; ++u) wc[u] = wa[u];
#pragma unroll
        for (int u = 0; u < UF; ++u) wa[u] = wp[(size_t)(kpa + u) * NC];
#pragma unroll
        for (int u4 = 0; u4 < UF / 4; ++u4) {
            float4 av[R];
#pragma unroll
            for (int r = 0; r < R; ++r)
                av[r] = *(const float4*)&s_in[r * in_stride + k0 + u4 * 4];
#pragma unroll
            for (int uu = 0; uu < 4; ++uu)
#pragma unroll
                for (int r = 0; r < R; ++r)
                    acc[r] += ((const float*)&av[r])[uu] * wc[u4 * 4 + uu];
        }

#pragma unroll
        for (int u = 0; u < UF; ++u) wc[u] = wb[u];
#pragma unroll
        for (int u = 0; u < UF; ++u) wb[u] = wp[(size_t)(kpb + u) * NC];
#pragma unroll
        for (int u4 = 0; u4 < UF / 4; ++u4) {
            float4 av[R];
#pragma unroll
            for (int r = 0; r < R; ++r)
                av[r] = *(const float4*)&s_in[r * in_stride + k0 + UF + u4 * 4];
#pragma unroll
            for (int uu = 0; uu < 4; ++uu)
#pragma unroll
                for (int r = 0; r < R; ++r)
                    acc[r] += ((const float*)&av[r])[uu] * wc[u4 * 4 + uu];
        }
    }

    float bv = bias[j];
#pragma unroll
    for (int r = 0; r < R; ++r) {
        float v = acc[r] + bv;
        if (POST_SILU) v = silu_f(v);
        outp[r * out_stride + j] = v;
    }
}

// Fused time-embedding MLP: emb -> silu(.@w1+b1) -> silu(.@w2+b2) -> .@wm+bm
// (silu of t2 folded into stage-2's write; stage 3 has no activation before @wm
//  per reference: mod = silu(t_emb) @ wm + bm.)
// One block = R=4 batch rows, T=512 threads, activations live in LDS.
template <int R>
__global__ __launch_bounds__(512) void k_mlp(const float* __restrict__ t,
                                             const float* __restrict__ w1, const float* __restrict__ b1,
                                             const float* __restrict__ w2, const float* __restrict__ b2,
                                             const float* __restrict__ wm, const float* __restrict__ bm,
                                             float* __restrict__ mb) {
    __shared__ __align__(16) float s_x[R][TDIM];
    __shared__ __align__(16) float s_y[R][TDIM];
    __shared__ float s_t[R];

    int tid = threadIdx.x;
    int row0 = blockIdx.x * R;

    if (tid < R) s_t[tid] = t[row0 + tid];
    __syncthreads();

    // timestep embedding into s_x[r][0..255]
    const float lm = 9.210340371976184f;   // ln(10000)
    for (int idx = tid; idx < R * FREQ_DIM; idx += 512) {
        int r = idx >> 8, j = idx & 255;
        int h = j & 127;
        float freq = expf(-lm * (float)h * (1.0f / 128.0f));
        float arg = s_t[r] * freq;
        s_x[r][j] = (j < 128) ? cosf(arg) : sinf(arg);
    }
    __syncthreads();

    mlp_stage<FREQ_DIM, TDIM, R, true >(&s_x[0][0], TDIM, w1, b1, &s_y[0][0], TDIM, tid);
    __syncthreads();
    mlp_stage<TDIM,     TDIM, R, true >(&s_y[0][0], TDIM, w2, b2, &s_x[0][0], TDIM, tid);
    __syncthreads();
    mlp_stage<TDIM,     MODC, R, false>(&s_x[0][0], TDIM, wm, bm, mb + (size_t)row0 * MODC, MODC, tid);
}

// One wave (64 lanes) per node. Row = 480 f32 = 120 float4.
// float4 idx:  0..31 -> seg0 (layernorm, floats 0..127)
//             32..79 -> seg1 (floats 128..319, 192 elems)
//             80..119-> seg2 (floats 320..479, 160 elems)
__global__ __launch_bounds__(256) void k_main(const float* __restrict__ x,
                                              const int* __restrict__ batch,
                                              const float* __restrict__ mod,
                                              float* __restrict__ out, int N) {
    int node = blockIdx.x * 4 + (threadIdx.x >> 6);
    if (node >= N) return;
    int lane = threadIdx.x & 63;

    const float4* rp = (const float4*)(x + (size_t)node * 480);
    float4 a = rp[lane];                         // f4 idx lane (0..63)
    float4 c = make_float4(0.f, 0.f, 0.f, 0.f);
    if (lane < 56) c = rp[64 + lane];            // f4 idx 64..119

    float s0 = 0.f, q0 = 0.f, q1 = 0.f, q2 = 0.f;
    float da = a.x * a.x + a.y * a.y + a.z * a.z + a.w * a.w;
    if (lane < 32) { s0 = a.x + a.y + a.z + a.w; q0 = da; }
    else           { q1 = da; }
    float dc = c.x * c.x + c.y * c.y + c.z * c.z + c.w * c.w;
    if (lane < 16)      q1 += dc;
    else if (lane < 56) q2 = dc;

#pragma unroll
    for (int m = 1; m < 64; m <<= 1) {
        s0 += __shfl_xor(s0, m, 64);
        q0 += __shfl_xor(q0, m, 64);
        q1 += __shfl_xor(q1, m, 64);
        q2 += __shfl_xor(q2, m, 64);
    }

    int b = batch[node];
    const float* mrow = mod + (size_t)b * MODC;
    float4 m4 = *(const float4*)mrow;            // cols 0..3 (need 0,1,2)

    float mean = s0 * (1.0f / 128.0f);
    float var  = q0 * (1.0f / 128.0f) - mean * mean;
    float r0 = rsqrtf(var + EPS) * (1.0f + m4.x);
    float r1 = rsqrtf(q1 * (1.0f / 192.0f) + EPS) * (1.0f + m4.y);
    float r2 = rsqrtf(q2 * (1.0f / 160.0f) + EPS) * (1.0f + m4.z);

    float4* op = (float4*)(out + (size_t)node * 480);
    float4 o;
    if (lane < 32) {
        float4 sh = *(const float4*)(mrow + 224 + 4 * lane);
        o.x = (a.x - mean) * r0 + sh.x;
        o.y = (a.y - mean) * r0 + sh.y;
        o.z = (a.z - mean) * r0 + sh.z;
        o.w = (a.w - mean) * r0 + sh.w;
    } else {
        o.x = a.x * r1; o.y = a.y * r1; o.z = a.z * r1; o.w = a.w * r1;
    }
    op[lane] = o;
    if (lane < 56) {
        float rr = (lane < 16) ? r1 : r2;
        float4 o2;
        o2.x = c.x * rr; o2.y = c.y * rr; o2.z = c.z * rr; o2.w = c.w * rr;
        op[64 + lane] = o2;
    }
}

extern "C" void kernel_launch(void* const* d_in, const int* in_sizes, int n_in,
                              void* d_out, int out_size, void* d_ws, size_t ws_size,
                              hipStream_t stream) {
    const float* node_input = (const float*)d_in[0];
    const float* t          = (const float*)d_in[1];
    const int*   batch      = (const int*)d_in[2];
    const float* w1         = (const float*)d_in[3];
    const float* b1         = (const float*)d_in[4];
    const float* w2         = (const float*)d_in[5];
    const float* b2         = (const float*)d_in[6];
    const float* wm         = (const float*)d_in[7];
    const float* bm         = (const float*)d_in[8];
    float* out = (float*)d_out;

    int N = in_sizes[0] / 480;   // 100000
    int B = in_sizes[1];         // 1024

    float* mb = (float*)d_ws;    // B*352 f32

    constexpr int R = 4;
    k_mlp<R><<<B / R, 512, 0, stream>>>(t, w1, b1, w2, b2, wm, bm, mb);
    k_main<<<(N + 3) / 4, 256, 0, stream>>>(node_input, batch, mb, out, N);
}